// Round 9
// baseline (220.932 us; speedup 1.0000x reference)
//
#include <hip/hip_runtime.h>

typedef unsigned short u16;
typedef __bf16 bf16_t;
typedef bf16_t bf16x8 __attribute__((ext_vector_type(8)));
typedef float f32x4 __attribute__((ext_vector_type(4)));
typedef u16 u16x8 __attribute__((ext_vector_type(8)));

#define T_SZ 2048
#define EMB 1024

static __device__ __forceinline__ u16 f2bf(float f) {
  union { float f; unsigned u; } v; v.f = f;
  return (u16)((v.u + 0x7fffu + ((v.u >> 16) & 1u)) >> 16);  // RNE
}
// Packed f32x2 -> bf16x2 (single HW instruction).
static __device__ __forceinline__ unsigned cvtpk(float a, float b) {
  unsigned r;
  asm("v_cvt_pk_bf16_f32 %0, %1, %2" : "=v"(r) : "v"(a), "v"(b));
  return r;  // low 16 = bf16(a), high 16 = bf16(b)
}
static __device__ __forceinline__ void async16(const u16* g, u16* l) {
  typedef const __attribute__((address_space(1))) unsigned int* gp_t;
  typedef __attribute__((address_space(3))) unsigned int* lp_t;
  // LDS dest = wave-uniform base + lane*16.  Per-lane (even permuted) global
  // source addresses proven correct by the R4<->R7 absmax-identity oracle.
  __builtin_amdgcn_global_load_lds((gp_t)(const void*)g, (lp_t)(void*)l, 16, 0, 0);
}

// One fused fp32->bf16 convert for all 5 tensors (proven R6/R8).
__global__ __launch_bounds__(256) void cvt_all(
    const float* __restrict__ x,  const float* __restrict__ Wq,
    const float* __restrict__ Wk, const float* __restrict__ Wv,
    const float* __restrict__ Wp, u16* __restrict__ xb, u16* __restrict__ Wqb,
    u16* __restrict__ Wkb, u16* __restrict__ Wvb, u16* __restrict__ Wpb) {
  int bid = blockIdx.x;
  const float* src; u16* dst; int off;
  if (bid < 4096)      { src = x;  dst = xb;  off = bid * 2048; }
  else if (bid < 4608) { src = Wq; dst = Wqb; off = (bid - 4096) * 2048; }
  else if (bid < 4736) { src = Wk; dst = Wkb; off = (bid - 4608) * 2048; }
  else if (bid < 4864) { src = Wv; dst = Wvb; off = (bid - 4736) * 2048; }
  else                 { src = Wp; dst = Wpb; off = (bid - 4864) * 2048; }
  int i = off + threadIdx.x * 8;
  float4 a = *(const float4*)(src + i);
  float4 b = *(const float4*)(src + i + 4);
  u16x8 o;
  o[0] = f2bf(a.x); o[1] = f2bf(a.y); o[2] = f2bf(a.z); o[3] = f2bf(a.w);
  o[4] = f2bf(b.x); o[5] = f2bf(b.y); o[6] = f2bf(b.z); o[7] = f2bf(b.w);
  *(u16x8*)(dst + i) = o;
}

// V [b*T][g*64+d] -> Vt [(b*4+g)*64+d][T].  (proven)
__global__ __launch_bounds__(256) void transpose_v(
    const u16* __restrict__ V, u16* __restrict__ Vt) {
  __shared__ u16 tile[64][72];
  const int tt = blockIdx.x, g = blockIdx.y, b = blockIdx.z;
  const int tid = threadIdx.x;
  {
    const int r = tid >> 2, c = (tid & 3) * 16;
    const u16* src = V + ((size_t)(b * T_SZ + tt * 64 + r)) * 256 + g * 64 + c;
    *(u16x8*)&tile[r][c] = *(const u16x8*)src;
    *(u16x8*)&tile[r][c + 8] = *(const u16x8*)(src + 8);
  }
  __syncthreads();
  {
    const int d = tid >> 2, t0 = (tid & 3) * 16;
    u16x8 o0, o1;
#pragma unroll
    for (int i = 0; i < 8; ++i) { o0[i] = tile[t0 + i][d]; o1[i] = tile[t0 + 8 + i][d]; }
    u16* dst = Vt + ((size_t)((b * 4 + g) * 64 + d)) * T_SZ + tt * 64 + t0;
    *(u16x8*)dst = o0;
    *(u16x8*)(dst + 8) = o1;
  }
}

// GEMM body with XOR-swizzled gather staging (proven R8).  Optional output
// scale cmul (wave-uniform) so gemm_qkv can pre-scale Q by 0.125*log2(e).
template <bool OUT_F32>
__device__ __forceinline__ void gemm_body(
    const u16* __restrict__ A, const u16* __restrict__ Bm,
    const float* __restrict__ bias, void* __restrict__ Cv,
    int N, int K, int tm, int tn, float cmul) {
  __shared__ u16 as[128 * 64];
  __shared__ u16 bs[128 * 64];
  const int tid = threadIdx.x;
  const int lane = tid & 63, wv = tid >> 6;
  const int quad = lane >> 4, l16 = lane & 15;
  const int wm = (wv & 1) * 64, wn = (wv >> 1) * 64;
  const int rA = lane >> 3;
  const int cS = ((lane & 7) ^ (rA & 7)) * 8;
  const int x7 = l16 & 7;
  f32x4 acc[4][4] = {};
  for (int k0 = 0; k0 < K; k0 += 64) {
#pragma unroll
    for (int it = 0; it < 4; ++it) {
      int r0 = it * 32 + wv * 8;
      async16(A + (size_t)(tm + r0 + rA) * K + k0 + cS, &as[r0 * 64]);
      async16(Bm + (size_t)(tn + r0 + rA) * K + k0 + cS, &bs[r0 * 64]);
    }
    __syncthreads();
#pragma unroll
    for (int kk = 0; kk < 64; kk += 32) {
      const int cb = kk >> 3;
      bf16x8 af[4], bfr[4];
#pragma unroll
      for (int i = 0; i < 4; ++i)
        af[i] = *(const bf16x8*)&as[(wm + i * 16 + l16) * 64 + (((cb + quad) ^ x7) * 8)];
#pragma unroll
      for (int j = 0; j < 4; ++j)
        bfr[j] = *(const bf16x8*)&bs[(wn + j * 16 + l16) * 64 + (((cb + quad) ^ x7) * 8)];
#pragma unroll
      for (int i = 0; i < 4; ++i)
#pragma unroll
        for (int j = 0; j < 4; ++j)
          acc[i][j] = __builtin_amdgcn_mfma_f32_16x16x32_bf16(af[i], bfr[j], acc[i][j], 0, 0, 0);
    }
    __syncthreads();
  }
#pragma unroll
  for (int i = 0; i < 4; ++i)
#pragma unroll
    for (int j = 0; j < 4; ++j) {
      int col = tn + wn + j * 16 + l16;
      float bv = bias ? bias[col] : 0.0f;
#pragma unroll
      for (int r = 0; r < 4; ++r) {
        int row = tm + wm + i * 16 + quad * 4 + r;
        if (OUT_F32)
          ((float*)Cv)[(size_t)row * N + col] = acc[i][j][r] + bv;
        else
          ((u16*)Cv)[(size_t)row * N + col] = f2bf(acc[i][j][r] * cmul + bv);
      }
    }
}

// Fused Q/K/V projection (proven R8).  Q output pre-scaled by SCALE2.
__global__ __launch_bounds__(256, 2) void gemm_qkv(
    const u16* __restrict__ x, const u16* __restrict__ Wq,
    const u16* __restrict__ Wk, const u16* __restrict__ Wv,
    u16* __restrict__ Qb, u16* __restrict__ Kb, u16* __restrict__ Vb) {
  const int y = blockIdx.y;
  const u16* Bm; u16* C; int N, tn; float cm;
  const float SCALE2 = 0.18033688011112042f;  // 0.125 * log2(e)
  if (y < 8)       { Bm = Wq; C = Qb; N = 1024; tn = y * 128;        cm = SCALE2; }
  else if (y < 10) { Bm = Wk; C = Kb; N = 256;  tn = (y - 8) * 128;  cm = 1.0f; }
  else             { Bm = Wv; C = Vb; N = 256;  tn = (y - 10) * 128; cm = 1.0f; }
  gemm_body<false>(x, Bm, nullptr, C, N, 1024, blockIdx.x * 128, tn, cm);
}

// Output projection, fp32 out + bias (proven R8).
__global__ __launch_bounds__(256, 2) void gemm_out(
    const u16* __restrict__ A, const u16* __restrict__ Wp,
    const float* __restrict__ bias, float* __restrict__ C) {
  gemm_body<true>(A, Wp, bias, C, 1024, 1024, blockIdx.x * 128, blockIdx.y * 128, 1.0f);
}

// Flash attention, causal, GQA.  R17: QBLK=64 restructure for barrier
// independence.  R16 kept 2x 8-wave blocks/CU (16 waves, 2 barrier domains);
// floor arithmetic (LDS ~15us, VALU ~14us vs 72us measured) says the loss is
// lockstep serialization.  Now: 256-thread blocks (4 waves), one 64-row
// q-strip pair {31-pr, pr} per block (nkt sum = 33, IDENTICAL for all
// blocks), grid 1024 -> 4 independent blocks/CU (same 16 waves, 4 barrier
// domains, barriers sync 4 waves not 8).  With 64-row strips every wave is
// active on every tile (8-wave version idled half the block on the last
// tile).  LDS = 2x(K,V) 64x64 dbuf (32KB, depth-1 R12 prefetch) + pls
// compacted to stride-64 with row-XOR swizzle (8KB) = 40960B exactly ->
// 4 x 40KB = 160KB exact fit.  pls swizzle (per row q=l16, x7=l16&7):
// write chunk16 = (jn*2+(quad>>1))^x7 (8B at +(quad&1)*8), read chunk16 =
// quad^x7 (pf0) / (4+quad)^x7 (pf1) -- same involution both sides.
// Keeps: fixed-max softmax, pre-scaled Q, diagonal-only mask, setprio,
// XCD-L2 decode (2 (b,g) per XCD).  launch_bounds(256,4): 128-VGPR budget,
// ~52 used -> no spill possible.
__global__ __launch_bounds__(256, 4) void gqa_attn(
    const u16* __restrict__ Q, const u16* __restrict__ Kg,
    const u16* __restrict__ Vt, u16* __restrict__ O) {
  __shared__ u16 kbuf[2][64 * 64];   // K-tile [kpos][d], swizzled      16KB
  __shared__ u16 vbuf[2][64 * 64];   // V^T-tile [d][kpos], swizzled    16KB
  __shared__ u16 pls[4][16 * 64];    // per-wave P [q][kpos], XOR-swz    8KB
  const int tid = threadIdx.x;
  const int lane = tid & 63, wv = tid >> 6;          // wv in 0..3
  const int quad = lane >> 4, l16 = lane & 15;
  const int bid = blockIdx.x;
  // Placement decode (validated model: XCD=bid&7, CU-slot=(bid>>3)&31,
  // co-resident quad = {bid, +256, +512, +768}):
  const int xcd = bid & 7;
  const int slot = (bid >> 3) & 31;
  const int w = bid >> 8;
  const int pr = slot & 15;                 // pair index: strips {31-pr, pr}
  const int bg = xcd + 8 * (w & 1);         // 2 (b,g) per XCD -> K/V L2-hot
  const int b = bg >> 2, g = bg & 3;
  const int h = g * 4 + (slot >> 4) + 2 * (w >> 1);
  const size_t bT = (size_t)b * T_SZ;
  const int rA = lane >> 3;
  const int cS = ((lane & 7) ^ (rA & 7)) * 8;  // swizzled source chunk offset
  const int x7 = l16 & 7;
  const u16* vtb = Vt + (size_t)((b * 4 + g) * 64) * T_SZ;
  char* pw = (char*)pls + wv * 2048 + l16 * 128;  // this lane's P row

#define STAGE(KT, BUF)                                                               \
  do {                                                                               \
    int kb_ = (KT) * 64, r0_ = wv * 16;  /* 4 waves x 16 rows = 64 */                \
    async16(Kg + (bT + kb_ + r0_ + rA) * 256 + g * 64 + cS, &kbuf[BUF][r0_ * 64]);   \
    async16(Kg + (bT + kb_ + r0_ + 8 + rA) * 256 + g * 64 + cS,                      \
            &kbuf[BUF][(r0_ + 8) * 64]);                                             \
    async16(vtb + (size_t)(r0_ + rA) * T_SZ + kb_ + cS, &vbuf[BUF][r0_ * 64]);       \
    async16(vtb + (size_t)(r0_ + 8 + rA) * T_SZ + kb_ + cS,                          \
            &vbuf[BUF][(r0_ + 8) * 64]);                                             \
    __builtin_amdgcn_sched_barrier(0);                                               \
  } while (0)

  for (int pass = 0; pass < 2; ++pass) {
    const int qs = pass ? pr : 31 - pr;     // 64-row strip index, heavy first
    const int qstrip = qs * 64 + wv * 16;
    const int nkt = qs + 1;

    // Q B-fragment (n = q = l16, k = quad*8+j); already SCALE2-scaled.
    const u16* qp = Q + (bT + qstrip + l16) * EMB + h * 64 + quad * 8;
    const bf16x8 qf0 = *(const bf16x8*)qp;
    const bf16x8 qf1 = *(const bf16x8*)(qp + 32);

    f32x4 o[4] = {};                 // O^C: [q=quad*4+r][d=j*16+l16]
    float l_p = 0.0f;                // per-lane (quad-partial) running sum

    __syncthreads();                 // pass boundary: prior buffer reads done
    STAGE(0, 0);
    for (int kt = 0; kt < nkt; ++kt) {
      const int cur = kt & 1;
      __syncthreads();               // drains stage(kt); orders buffer reuse
      if (kt + 1 < nkt) STAGE(kt + 1, cur ^ 1);
      const int kb = kt * 64;

      // S^T = K Q^T : s4[jn][r] = S[kpos=kt*64+jn*16+quad*4+r][q=qstrip+l16]
      f32x4 s4[4];
      __builtin_amdgcn_s_setprio(1);
#pragma unroll
      for (int jn = 0; jn < 4; ++jn) {
        const int rowb = (jn * 16 + l16) * 64;
        bf16x8 kf0 = *(const bf16x8*)&kbuf[cur][rowb + ((quad ^ x7) * 8)];
        bf16x8 kf1 = *(const bf16x8*)&kbuf[cur][rowb + (((4 + quad) ^ x7) * 8)];
        f32x4 a = {};
        a = __builtin_amdgcn_mfma_f32_16x16x32_bf16(kf0, qf0, a, 0, 0, 0);
        a = __builtin_amdgcn_mfma_f32_16x16x32_bf16(kf1, qf1, a, 0, 0, 0);
        s4[jn] = a;
      }
      __builtin_amdgcn_s_setprio(0);
      // Causal mask: only the diagonal tile (kt == qs) needs it.
      if (kb + 63 > qstrip) {
        const int qg = qstrip + l16;
#pragma unroll
        for (int jn = 0; jn < 4; ++jn)
#pragma unroll
          for (int r = 0; r < 4; ++r)
            if (kb + jn * 16 + quad * 4 + r > qg) s4[jn][r] = -1e30f;
      }
      // Fixed-max softmax: p = exp2(s2) (exp2(-1e30) = 0 for masked).
      float sj[4];
#pragma unroll
      for (int jn = 0; jn < 4; ++jn) {
#pragma unroll
        for (int r = 0; r < 4; ++r) s4[jn][r] = exp2f(s4[jn][r]);
        sj[jn] = (s4[jn][0] + s4[jn][1]) + (s4[jn][2] + s4[jn][3]);
      }
      l_p += (sj[0] + sj[1]) + (sj[2] + sj[3]);
      // P store: packed cvt, swizzled chunk; 4 consecutive kpos -> 8B write.
#pragma unroll
      for (int jn = 0; jn < 4; ++jn) {
        uint2 wq;
        wq.x = cvtpk(s4[jn][0], s4[jn][1]);
        wq.y = cvtpk(s4[jn][2], s4[jn][3]);
        *(uint2*)(pw + ((((jn * 2 + (quad >> 1)) ^ x7) * 16) | ((quad & 1) * 8))) = wq;
      }
      // PV: per-wave P round-trip ordered by lgkmcnt (no barrier needed).
      bf16x8 pf0 = *(const bf16x8*)(pw + ((quad ^ x7) * 16));
      bf16x8 pf1 = *(const bf16x8*)(pw + (((4 + quad) ^ x7) * 16));
      __builtin_amdgcn_s_setprio(1);
#pragma unroll
      for (int j = 0; j < 4; ++j) {
        const int rowb = (j * 16 + l16) * 64;
        bf16x8 vf0 = *(const bf16x8*)&vbuf[cur][rowb + ((quad ^ x7) * 8)];
        bf16x8 vf1 = *(const bf16x8*)&vbuf[cur][rowb + (((4 + quad) ^ x7) * 8)];
        o[j] = __builtin_amdgcn_mfma_f32_16x16x32_bf16(pf0, vf0, o[j], 0, 0, 0);
        o[j] = __builtin_amdgcn_mfma_f32_16x16x32_bf16(pf1, vf1, o[j], 0, 0, 0);
      }
      __builtin_amdgcn_s_setprio(0);
    }
    // Cross-quad row-sum reduce, normalize + write.
    float l_l = l_p;
    l_l += __shfl_xor(l_l, 16);
    l_l += __shfl_xor(l_l, 32);
#pragma unroll
    for (int r = 0; r < 4; ++r) {
      float inv = 1.0f / __shfl(l_l, quad * 4 + r, 16);
      int row = qstrip + quad * 4 + r;
#pragma unroll
      for (int j = 0; j < 4; ++j)
        O[(bT + row) * EMB + h * 64 + j * 16 + l16] = f2bf(o[j][r] * inv);
    }
  }
#undef STAGE
}

extern "C" void kernel_launch(void* const* d_in, const int* in_sizes, int n_in,
                              void* d_out, int out_size, void* d_ws, size_t ws_size,
                              hipStream_t stream) {
  const float* x  = (const float*)d_in[0];
  const float* Wq = (const float*)d_in[1];
  const float* Wk = (const float*)d_in[2];
  const float* Wv = (const float*)d_in[3];
  const float* Wp = (const float*)d_in[4];
  const float* bp = (const float*)d_in[5];
  float* out = (float*)d_out;

  u16* ws = (u16*)d_ws;
  u16* Qb  = ws;                              // 8M u16
  u16* Kb  = Qb + (size_t)8192 * 1024;        // 2M
  u16* Vb  = Kb + (size_t)8192 * 256;         // 2M
  u16* Vtb = Vb + (size_t)8192 * 256;         // 2M
  u16* xb  = Vtb + (size_t)8192 * 256;        // 8M (reused as Ab after QKV)
  u16* Wqb = xb + (size_t)8192 * 1024;        // 1M
  u16* Wkb = Wqb + (size_t)1024 * 1024;       // 256K
  u16* Wvb = Wkb + (size_t)256 * 1024;        // 256K
  u16* Wpb = Wvb + (size_t)256 * 1024;        // 1M  -> 24.5M u16 = 49 MB
  u16* Ab  = xb;                              // alias: x dead after QKV GEMM

  cvt_all<<<dim3(5376), 256, 0, stream>>>(x, Wq, Wk, Wv, Wp, xb, Wqb, Wkb, Wvb, Wpb);
  gemm_qkv<<<dim3(64, 12), 256, 0, stream>>>(xb, Wqb, Wkb, Wvb, Qb, Kb, Vb);
  transpose_v<<<dim3(32, 4, 4), 256, 0, stream>>>(Vb, Vtb);
  gqa_attn<<<dim3(1024), 256, 0, stream>>>(Qb, Kb, Vtb, Ab);
  gemm_out<<<dim3(64, 8), 256, 0, stream>>>(Ab, Wpb, bp, out);
}

// Round 10
// 212.554 us; speedup vs baseline: 1.0394x; 1.0394x over previous
//
#include <hip/hip_runtime.h>

typedef unsigned short u16;
typedef __bf16 bf16_t;
typedef bf16_t bf16x8 __attribute__((ext_vector_type(8)));
typedef float f32x4 __attribute__((ext_vector_type(4)));
typedef u16 u16x8 __attribute__((ext_vector_type(8)));

#define T_SZ 2048
#define EMB 1024

static __device__ __forceinline__ u16 f2bf(float f) {
  union { float f; unsigned u; } v; v.f = f;
  return (u16)((v.u + 0x7fffu + ((v.u >> 16) & 1u)) >> 16);  // RNE
}
// Packed f32x2 -> bf16x2 (single HW instruction).
static __device__ __forceinline__ unsigned cvtpk(float a, float b) {
  unsigned r;
  asm("v_cvt_pk_bf16_f32 %0, %1, %2" : "=v"(r) : "v"(a), "v"(b));
  return r;  // low 16 = bf16(a), high 16 = bf16(b)
}
static __device__ __forceinline__ void async16(const u16* g, u16* l) {
  typedef const __attribute__((address_space(1))) unsigned int* gp_t;
  typedef __attribute__((address_space(3))) unsigned int* lp_t;
  // LDS dest = wave-uniform base + lane*16.  Per-lane (even permuted) global
  // source addresses proven correct by the R4<->R7 absmax-identity oracle.
  __builtin_amdgcn_global_load_lds((gp_t)(const void*)g, (lp_t)(void*)l, 16, 0, 0);
}

// One fused fp32->bf16 convert for all 5 tensors (proven R6/R8).
__global__ __launch_bounds__(256) void cvt_all(
    const float* __restrict__ x,  const float* __restrict__ Wq,
    const float* __restrict__ Wk, const float* __restrict__ Wv,
    const float* __restrict__ Wp, u16* __restrict__ xb, u16* __restrict__ Wqb,
    u16* __restrict__ Wkb, u16* __restrict__ Wvb, u16* __restrict__ Wpb) {
  int bid = blockIdx.x;
  const float* src; u16* dst; int off;
  if (bid < 4096)      { src = x;  dst = xb;  off = bid * 2048; }
  else if (bid < 4608) { src = Wq; dst = Wqb; off = (bid - 4096) * 2048; }
  else if (bid < 4736) { src = Wk; dst = Wkb; off = (bid - 4608) * 2048; }
  else if (bid < 4864) { src = Wv; dst = Wvb; off = (bid - 4736) * 2048; }
  else                 { src = Wp; dst = Wpb; off = (bid - 4864) * 2048; }
  int i = off + threadIdx.x * 8;
  float4 a = *(const float4*)(src + i);
  float4 b = *(const float4*)(src + i + 4);
  u16x8 o;
  o[0] = f2bf(a.x); o[1] = f2bf(a.y); o[2] = f2bf(a.z); o[3] = f2bf(a.w);
  o[4] = f2bf(b.x); o[5] = f2bf(b.y); o[6] = f2bf(b.z); o[7] = f2bf(b.w);
  *(u16x8*)(dst + i) = o;
}

// V [b*T][g*64+d] -> Vt [(b*4+g)*64+d][T].  (proven)
__global__ __launch_bounds__(256) void transpose_v(
    const u16* __restrict__ V, u16* __restrict__ Vt) {
  __shared__ u16 tile[64][72];
  const int tt = blockIdx.x, g = blockIdx.y, b = blockIdx.z;
  const int tid = threadIdx.x;
  {
    const int r = tid >> 2, c = (tid & 3) * 16;
    const u16* src = V + ((size_t)(b * T_SZ + tt * 64 + r)) * 256 + g * 64 + c;
    *(u16x8*)&tile[r][c] = *(const u16x8*)src;
    *(u16x8*)&tile[r][c + 8] = *(const u16x8*)(src + 8);
  }
  __syncthreads();
  {
    const int d = tid >> 2, t0 = (tid & 3) * 16;
    u16x8 o0, o1;
#pragma unroll
    for (int i = 0; i < 8; ++i) { o0[i] = tile[t0 + i][d]; o1[i] = tile[t0 + 8 + i][d]; }
    u16* dst = Vt + ((size_t)((b * 4 + g) * 64 + d)) * T_SZ + tt * 64 + t0;
    *(u16x8*)dst = o0;
    *(u16x8*)(dst + 8) = o1;
  }
}

// GEMM body with XOR-swizzled gather staging (proven R8).  Optional output
// scale cmul (wave-uniform) so gemm_qkv can pre-scale Q by 0.125*log2(e).
template <bool OUT_F32>
__device__ __forceinline__ void gemm_body(
    const u16* __restrict__ A, const u16* __restrict__ Bm,
    const float* __restrict__ bias, void* __restrict__ Cv,
    int N, int K, int tm, int tn, float cmul) {
  __shared__ u16 as[128 * 64];
  __shared__ u16 bs[128 * 64];
  const int tid = threadIdx.x;
  const int lane = tid & 63, wv = tid >> 6;
  const int quad = lane >> 4, l16 = lane & 15;
  const int wm = (wv & 1) * 64, wn = (wv >> 1) * 64;
  const int rA = lane >> 3;
  const int cS = ((lane & 7) ^ (rA & 7)) * 8;
  const int x7 = l16 & 7;
  f32x4 acc[4][4] = {};
  for (int k0 = 0; k0 < K; k0 += 64) {
#pragma unroll
    for (int it = 0; it < 4; ++it) {
      int r0 = it * 32 + wv * 8;
      async16(A + (size_t)(tm + r0 + rA) * K + k0 + cS, &as[r0 * 64]);
      async16(Bm + (size_t)(tn + r0 + rA) * K + k0 + cS, &bs[r0 * 64]);
    }
    __syncthreads();
#pragma unroll
    for (int kk = 0; kk < 64; kk += 32) {
      const int cb = kk >> 3;
      bf16x8 af[4], bfr[4];
#pragma unroll
      for (int i = 0; i < 4; ++i)
        af[i] = *(const bf16x8*)&as[(wm + i * 16 + l16) * 64 + (((cb + quad) ^ x7) * 8)];
#pragma unroll
      for (int j = 0; j < 4; ++j)
        bfr[j] = *(const bf16x8*)&bs[(wn + j * 16 + l16) * 64 + (((cb + quad) ^ x7) * 8)];
#pragma unroll
      for (int i = 0; i < 4; ++i)
#pragma unroll
        for (int j = 0; j < 4; ++j)
          acc[i][j] = __builtin_amdgcn_mfma_f32_16x16x32_bf16(af[i], bfr[j], acc[i][j], 0, 0, 0);
    }
    __syncthreads();
  }
#pragma unroll
  for (int i = 0; i < 4; ++i)
#pragma unroll
    for (int j = 0; j < 4; ++j) {
      int col = tn + wn + j * 16 + l16;
      float bv = bias ? bias[col] : 0.0f;
#pragma unroll
      for (int r = 0; r < 4; ++r) {
        int row = tm + wm + i * 16 + quad * 4 + r;
        if (OUT_F32)
          ((float*)Cv)[(size_t)row * N + col] = acc[i][j][r] + bv;
        else
          ((u16*)Cv)[(size_t)row * N + col] = f2bf(acc[i][j][r] * cmul + bv);
      }
    }
}

// Fused Q/K/V projection (proven R8).  Q output pre-scaled by SCALE2.
__global__ __launch_bounds__(256, 2) void gemm_qkv(
    const u16* __restrict__ x, const u16* __restrict__ Wq,
    const u16* __restrict__ Wk, const u16* __restrict__ Wv,
    u16* __restrict__ Qb, u16* __restrict__ Kb, u16* __restrict__ Vb) {
  const int y = blockIdx.y;
  const u16* Bm; u16* C; int N, tn; float cm;
  const float SCALE2 = 0.18033688011112042f;  // 0.125 * log2(e)
  if (y < 8)       { Bm = Wq; C = Qb; N = 1024; tn = y * 128;        cm = SCALE2; }
  else if (y < 10) { Bm = Wk; C = Kb; N = 256;  tn = (y - 8) * 128;  cm = 1.0f; }
  else             { Bm = Wv; C = Vb; N = 256;  tn = (y - 10) * 128; cm = 1.0f; }
  gemm_body<false>(x, Bm, nullptr, C, N, 1024, blockIdx.x * 128, tn, cm);
}

// Output projection, fp32 out + bias (proven R8).
__global__ __launch_bounds__(256, 2) void gemm_out(
    const u16* __restrict__ A, const u16* __restrict__ Wp,
    const float* __restrict__ bias, float* __restrict__ C) {
  gemm_body<true>(A, Wp, bias, C, 1024, 1024, blockIdx.x * 128, blockIdx.y * 128, 1.0f);
}

// Flash attention, causal, GQA.  R18: 32 q-rows per wave to cut LDS-read
// bandwidth, the measured binding floor of R16 (2.7 GB frag reads ~= 39us
// of the 72).  Each wave owns two 16-row halves (q = qstrip+l16 and +16);
// kf/vf LDS fragments are read ONCE into registers and feed both halves'
// MFMAs: per-wave per-tile LDS = K8 + V8 + P4+4 = 24 KB per 32 q vs R16's
// 20 KB per 16 q (-40%/q); block-tiles, barriers and K/V staging all halve.
// Block = 8 waves x 32 q = one 256-row strip; nkt = 4qs+4.  Grid 512 on the
// validated placement model (XCD=bid&7, CU-slot=(bid>>3)&31, co-resident =
// {bid, bid+256}):  bg = xcd + 8*(slot&1)  (2 (b,g) per XCD -> K/V L2-hot);
// h = g*4 + ((slot>>1)&3);  c = (slot>>3)&3;  qs = w ? 7-c : c  ->
// co-resident pair (c, 7-c): nkt sum = 36 tiles per CU, uniform.  LDS =
// 2x16 KB K/V dbuf + pls 8x32x72 (36 KB) = 69.6 KB -> 2 blocks/CU (139 KB).
// Depth-1 __syncthreads prefetch (R17-proven): each stage has a full
// (2x-longer) tile of compute to land -> drain ~free.  VGPR ~105 under the
// (512,4) 128 cap; keeps fixed-max softmax, pre-scaled Q, diagonal-only
// mask, setprio.
__global__ __launch_bounds__(512, 4) void gqa_attn(
    const u16* __restrict__ Q, const u16* __restrict__ Kg,
    const u16* __restrict__ Vt, u16* __restrict__ O) {
  __shared__ u16 kbuf[2][64 * 64];   // K-tile [kpos][d], swizzled
  __shared__ u16 vbuf[2][64 * 64];   // V^T-tile [d][kpos], swizzled
  __shared__ u16 pls[8][32 * 72];    // per-wave P [qlocal 0..31][kpos]
  const int tid = threadIdx.x;
  const int lane = tid & 63, wv = tid >> 6;
  const int quad = lane >> 4, l16 = lane & 15;
  const int bid = blockIdx.x;
  const int xcd = bid & 7, slot = (bid >> 3) & 31, w = bid >> 8;
  const int bg = xcd + 8 * (slot & 1);
  const int b = bg >> 2, g = bg & 3;
  const int h = g * 4 + ((slot >> 1) & 3);
  const int c = (slot >> 3) & 3;
  const int qs = w ? 7 - c : c;           // 256-row strip index 0..7
  const int nkt = 4 * qs + 4;
  const int qstrip = qs * 256 + wv * 32;
  const size_t bT = (size_t)b * T_SZ;
  const int rA = lane >> 3;
  const int cS = ((lane & 7) ^ (rA & 7)) * 8;  // swizzled source chunk offset
  const int x7 = l16 & 7;
  const u16* vtb = Vt + (size_t)((b * 4 + g) * 64) * T_SZ;

#define STAGE(KT, BUF)                                                              \
  do {                                                                              \
    int kb_ = (KT) * 64, r0_ = wv * 8;  /* 8 waves x 8 rows = 64 */                 \
    async16(Kg + (bT + kb_ + r0_ + rA) * 256 + g * 64 + cS, &kbuf[BUF][r0_ * 64]);  \
    async16(vtb + (size_t)(r0_ + rA) * T_SZ + kb_ + cS, &vbuf[BUF][r0_ * 64]);      \
    __builtin_amdgcn_sched_barrier(0);                                              \
  } while (0)

  // Q B-fragments for both 16-row halves; already SCALE2-scaled.
  const u16* qpa = Q + (bT + qstrip + l16) * EMB + h * 64 + quad * 8;
  const u16* qpb = qpa + 16 * EMB;
  const bf16x8 qf0a = *(const bf16x8*)qpa;
  const bf16x8 qf1a = *(const bf16x8*)(qpa + 32);
  const bf16x8 qf0b = *(const bf16x8*)qpb;
  const bf16x8 qf1b = *(const bf16x8*)(qpb + 32);

  f32x4 oa[4] = {}, ob[4] = {};    // O^C per half: [q=quad*4+r][d=j*16+l16]
  float lpa = 0.0f, lpb = 0.0f;    // per-lane (quad-partial) row sums

  STAGE(0, 0);
  for (int kt = 0; kt < nkt; ++kt) {
    const int cur = kt & 1;
    __syncthreads();               // stage(kt) landed; prev-iter reads done
    if (kt + 1 < nkt) STAGE(kt + 1, cur ^ 1);
    const int kb = kt * 64;
    const bool act = (kb <= qstrip + 31);  // wave-uniform

    if (act) {
      // S^T = K Q^T for both halves; kf read once, used twice.
      f32x4 sa[4], sb[4];
      __builtin_amdgcn_s_setprio(1);
#pragma unroll
      for (int jn = 0; jn < 4; ++jn) {
        const int rowb = (jn * 16 + l16) * 64;
        bf16x8 kf0 = *(const bf16x8*)&kbuf[cur][rowb + ((quad ^ x7) * 8)];
        bf16x8 kf1 = *(const bf16x8*)&kbuf[cur][rowb + (((4 + quad) ^ x7) * 8)];
        f32x4 a = {};
        a = __builtin_amdgcn_mfma_f32_16x16x32_bf16(kf0, qf0a, a, 0, 0, 0);
        a = __builtin_amdgcn_mfma_f32_16x16x32_bf16(kf1, qf1a, a, 0, 0, 0);
        sa[jn] = a;
        f32x4 bacc = {};
        bacc = __builtin_amdgcn_mfma_f32_16x16x32_bf16(kf0, qf0b, bacc, 0, 0, 0);
        bacc = __builtin_amdgcn_mfma_f32_16x16x32_bf16(kf1, qf1b, bacc, 0, 0, 0);
        sb[jn] = bacc;
      }
      __builtin_amdgcn_s_setprio(0);
      // Causal mask: only near-diagonal tiles need it.
      if (kb + 63 > qstrip) {
        const int qga = qstrip + l16, qgb = qstrip + 16 + l16;
#pragma unroll
        for (int jn = 0; jn < 4; ++jn)
#pragma unroll
          for (int r = 0; r < 4; ++r) {
            int kp = kb + jn * 16 + quad * 4 + r;
            if (kp > qga) sa[jn][r] = -1e30f;
            if (kp > qgb) sb[jn][r] = -1e30f;
          }
      }
      // Fixed-max softmax: p = exp2(s2); quad-partial row sums.
      float sja[4], sjb[4];
#pragma unroll
      for (int jn = 0; jn < 4; ++jn) {
#pragma unroll
        for (int r = 0; r < 4; ++r) {
          sa[jn][r] = exp2f(sa[jn][r]);
          sb[jn][r] = exp2f(sb[jn][r]);
        }
        sja[jn] = (sa[jn][0] + sa[jn][1]) + (sa[jn][2] + sa[jn][3]);
        sjb[jn] = (sb[jn][0] + sb[jn][1]) + (sb[jn][2] + sb[jn][3]);
      }
      lpa += (sja[0] + sja[1]) + (sja[2] + sja[3]);
      lpb += (sjb[0] + sjb[1]) + (sjb[2] + sjb[3]);
      // P store: rows l16 (half a) and 16+l16 (half b), stride 72.
#pragma unroll
      for (int jn = 0; jn < 4; ++jn) {
        uint2 wa, wb;
        wa.x = cvtpk(sa[jn][0], sa[jn][1]); wa.y = cvtpk(sa[jn][2], sa[jn][3]);
        wb.x = cvtpk(sb[jn][0], sb[jn][1]); wb.y = cvtpk(sb[jn][2], sb[jn][3]);
        *(uint2*)&pls[wv][l16 * 72 + jn * 16 + quad * 4] = wa;
        *(uint2*)&pls[wv][(16 + l16) * 72 + jn * 16 + quad * 4] = wb;
      }
      // PV: per-wave P round-trip (lgkm-ordered); vf read once, used twice.
      bf16x8 pf0a = *(const bf16x8*)&pls[wv][l16 * 72 + quad * 8];
      bf16x8 pf1a = *(const bf16x8*)&pls[wv][l16 * 72 + 32 + quad * 8];
      bf16x8 pf0b = *(const bf16x8*)&pls[wv][(16 + l16) * 72 + quad * 8];
      bf16x8 pf1b = *(const bf16x8*)&pls[wv][(16 + l16) * 72 + 32 + quad * 8];
      __builtin_amdgcn_s_setprio(1);
#pragma unroll
      for (int j = 0; j < 4; ++j) {
        const int rowb = (j * 16 + l16) * 64;
        bf16x8 vf0 = *(const bf16x8*)&vbuf[cur][rowb + ((quad ^ x7) * 8)];
        bf16x8 vf1 = *(const bf16x8*)&vbuf[cur][rowb + (((4 + quad) ^ x7) * 8)];
        oa[j] = __builtin_amdgcn_mfma_f32_16x16x32_bf16(pf0a, vf0, oa[j], 0, 0, 0);
        oa[j] = __builtin_amdgcn_mfma_f32_16x16x32_bf16(pf1a, vf1, oa[j], 0, 0, 0);
        ob[j] = __builtin_amdgcn_mfma_f32_16x16x32_bf16(pf0b, vf0, ob[j], 0, 0, 0);
        ob[j] = __builtin_amdgcn_mfma_f32_16x16x32_bf16(pf1b, vf1, ob[j], 0, 0, 0);
      }
      __builtin_amdgcn_s_setprio(0);
    }
  }
#undef STAGE
  // Cross-quad row-sum reduce, normalize + write, both halves.
  float lla = lpa;
  lla += __shfl_xor(lla, 16);
  lla += __shfl_xor(lla, 32);
  float llb = lpb;
  llb += __shfl_xor(llb, 16);
  llb += __shfl_xor(llb, 32);
#pragma unroll
  for (int r = 0; r < 4; ++r) {
    float inva = 1.0f / __shfl(lla, quad * 4 + r, 16);
    float invb = 1.0f / __shfl(llb, quad * 4 + r, 16);
    int rowa = qstrip + quad * 4 + r;
    int rowb_ = qstrip + 16 + quad * 4 + r;
#pragma unroll
    for (int j = 0; j < 4; ++j) {
      O[(bT + rowa) * EMB + h * 64 + j * 16 + l16] = f2bf(oa[j][r] * inva);
      O[(bT + rowb_) * EMB + h * 64 + j * 16 + l16] = f2bf(ob[j][r] * invb);
    }
  }
}

extern "C" void kernel_launch(void* const* d_in, const int* in_sizes, int n_in,
                              void* d_out, int out_size, void* d_ws, size_t ws_size,
                              hipStream_t stream) {
  const float* x  = (const float*)d_in[0];
  const float* Wq = (const float*)d_in[1];
  const float* Wk = (const float*)d_in[2];
  const float* Wv = (const float*)d_in[3];
  const float* Wp = (const float*)d_in[4];
  const float* bp = (const float*)d_in[5];
  float* out = (float*)d_out;

  u16* ws = (u16*)d_ws;
  u16* Qb  = ws;                              // 8M u16
  u16* Kb  = Qb + (size_t)8192 * 1024;        // 2M
  u16* Vb  = Kb + (size_t)8192 * 256;         // 2M
  u16* Vtb = Vb + (size_t)8192 * 256;         // 2M
  u16* xb  = Vtb + (size_t)8192 * 256;        // 8M (reused as Ab after QKV)
  u16* Wqb = xb + (size_t)8192 * 1024;        // 1M
  u16* Wkb = Wqb + (size_t)1024 * 1024;       // 256K
  u16* Wvb = Wkb + (size_t)256 * 1024;        // 256K
  u16* Wpb = Wvb + (size_t)256 * 1024;        // 1M  -> 24.5M u16 = 49 MB
  u16* Ab  = xb;                              // alias: x dead after QKV GEMM

  cvt_all<<<dim3(5376), 256, 0, stream>>>(x, Wq, Wk, Wv, Wp, xb, Wqb, Wkb, Wvb, Wpb);
  gemm_qkv<<<dim3(64, 12), 256, 0, stream>>>(xb, Wqb, Wkb, Wvb, Qb, Kb, Vb);
  transpose_v<<<dim3(32, 4, 4), 256, 0, stream>>>(Vb, Vtb);
  gqa_attn<<<dim3(512), 512, 0, stream>>>(Qb, Kb, Vtb, Ab);
  gemm_out<<<dim3(64, 8), 256, 0, stream>>>(Ab, Wpb, bp, out);
}